// Round 1
// baseline (250.322 us; speedup 1.0000x reference)
//
#include <hip/hip_runtime.h>

#define NNODES 40960
#define NEDGES 81920
#define NG     1024
#define NCOMBO 512

// ---------- atom encoder: x[n,d] = sum_c atom_emb[c, nf[n,c], d] ----------
__global__ void k_atom(const int* __restrict__ nf, const float* __restrict__ emb,
                       float* __restrict__ x) {
    int gid = blockIdx.x * blockDim.x + threadIdx.x;   // NNODES*64
    int n = gid >> 6, d = gid & 63;
    const int* nfr = nf + n * 9;
    float acc = 0.f;
#pragma unroll
    for (int c = 0; c < 9; ++c) {
        int idx = nfr[c];
        acc += emb[((c << 7) + idx) * 64 + d];
    }
    x[gid] = acc;
}

// ---------- out_init[n,o] = bias[o] + sum_d x[n,d]*root[d,o] ----------
__global__ void k_rootinit(const float* __restrict__ x, const float* __restrict__ root,
                           const float* __restrict__ bias, float* __restrict__ out) {
    int gid = blockIdx.x * blockDim.x + threadIdx.x;   // NNODES*32
    int n = gid >> 5, o = gid & 31;
    const float* xr = x + n * 64;
    float acc = bias[o];
#pragma unroll
    for (int d = 0; d < 64; ++d) acc += xr[d] * root[d * 32 + o];
    out[gid] = acc;
}

// ---------- zero 512 ints ----------
__global__ void k_zero512(int* __restrict__ p) { p[threadIdx.x] = 0; }

// ---------- fused: combo id per edge + histogram over 512 combos ----------
__global__ void k_cid_hist(const int* __restrict__ ef, int* __restrict__ cid,
                           int* __restrict__ hist) {
    __shared__ int lh[512];
    int t = threadIdx.x;
    lh[t] = 0; lh[t + 256] = 0;
    __syncthreads();
    int e = blockIdx.x * 256 + t;                      // NEDGES % 256 == 0
    int c = (ef[e * 3] << 6) | (ef[e * 3 + 1] << 3) | ef[e * 3 + 2];
    cid[e] = c;
    atomicAdd(&lh[c], 1);
    __syncthreads();
    if (lh[t])       atomicAdd(&hist[t], lh[t]);
    if (lh[t + 256]) atomicAdd(&hist[t + 256], lh[t + 256]);
}

// ---------- exclusive scan of 512 counts (single block, 512 threads) ----------
__global__ void k_scan(const int* __restrict__ hist, int* __restrict__ offs,
                       int* __restrict__ cursor) {
    __shared__ int tmp[512];
    int t = threadIdx.x;
    int v = hist[t];
    tmp[t] = v;
    __syncthreads();
    for (int d = 1; d < 512; d <<= 1) {
        int add = (t >= d) ? tmp[t - d] : 0;
        __syncthreads();
        tmp[t] += add;
        __syncthreads();
    }
    offs[t]   = tmp[t] - v;
    cursor[t] = tmp[t] - v;
    if (t == 511) offs[512] = tmp[511];
}

// ---------- bucket edges by combo: esd[p] = (src,dst), sorted by cid ----------
__global__ void k_scatter(const int* __restrict__ cid, const int* __restrict__ src,
                          const int* __restrict__ dst, int* __restrict__ cursor,
                          int2* __restrict__ esd) {
    int e = blockIdx.x * 256 + threadIdx.x;
    int p = atomicAdd(&cursor[cid[e]], 1);
    esd[p] = make_int2(src[e], dst[e]);
}

// ---------- etab[c,j] = sum of 3 bond embeddings ----------
__global__ void k_etab(const float* __restrict__ bemb, float* __restrict__ etab) {
    int gid = blockIdx.x * blockDim.x + threadIdx.x;   // 512*16
    int c = gid >> 4, j = gid & 15;
    int f0 = c >> 6, f1 = (c >> 3) & 7, f2 = c & 7;
    etab[gid] = bemb[(0 * 8 + f0) * 16 + j] + bemb[(1 * 8 + f1) * 16 + j] +
                bemb[(2 * 8 + f2) * 16 + j];
}

// ---------- naive GEMM (small K only): C = relu?(A@B + bias) ----------
__global__ void k_gemm_naive(const float* __restrict__ A, const float* __restrict__ B,
                             const float* __restrict__ bias, float* __restrict__ C,
                             int M, int N, int K, int relu) {
    int gid = blockIdx.x * blockDim.x + threadIdx.x;
    if (gid >= M * N) return;
    int m = gid / N, n = gid - m * N;
    const float* a = A + m * K;
    float acc = bias ? bias[n] : 0.f;
    for (int k = 0; k < K; ++k) acc += a[k] * B[k * N + n];
    if (relu) acc = fmaxf(acc, 0.f);
    C[gid] = acc;
}

// ---------- tiled GEMM, 64x64 block tile, 4x4 micro tile, split-K over z ----------
template <int BM, int BN, int BK, int TM, int TN>
__global__ __launch_bounds__(256)
void k_gemm_tiled(const float* __restrict__ A, const float* __restrict__ B,
                  const float* __restrict__ bias, float* __restrict__ C,
                  float* __restrict__ Cp, int M, int N, int K, int KS, int relu) {
    constexpr int TX = BN / TN;                 // 16
    constexpr int TY = BM / TM;                 // 16
    static_assert(TX * TY == 256, "block must be 256 threads");
    __shared__ float As[BK][BM + 4];            // transposed A tile
    __shared__ float Bs[BK][BN + 4];
    const int tx = threadIdx.x % TX, ty = threadIdx.x / TX;
    const int row0 = blockIdx.y * BM, col0 = blockIdx.x * BN;
    const int z = blockIdx.z;
    const int k_begin = z * KS, k_end = k_begin + KS;

    const int am = threadIdx.x >> 2;            // 0..63
    const int ak = (threadIdx.x & 3) << 2;      // 0,4,8,12
    const int bk = threadIdx.x >> 4;            // 0..15
    const int bn = (threadIdx.x & 15) << 2;     // 0..60

    float acc[TM][TN] = {};
    for (int k0 = k_begin; k0 < k_end; k0 += BK) {
        float4 av = *reinterpret_cast<const float4*>(&A[(row0 + am) * K + k0 + ak]);
        float4 bv = *reinterpret_cast<const float4*>(&B[(k0 + bk) * N + col0 + bn]);
        As[ak + 0][am] = av.x;
        As[ak + 1][am] = av.y;
        As[ak + 2][am] = av.z;
        As[ak + 3][am] = av.w;
        *reinterpret_cast<float4*>(&Bs[bk][bn]) = bv;
        __syncthreads();
#pragma unroll
        for (int k = 0; k < BK; ++k) {
            float a[TM], b[TN];
            *reinterpret_cast<float4*>(a) =
                *reinterpret_cast<const float4*>(&As[k][ty * TM]);
            *reinterpret_cast<float4*>(b) =
                *reinterpret_cast<const float4*>(&Bs[k][tx * TN]);
#pragma unroll
            for (int i = 0; i < TM; ++i)
#pragma unroll
                for (int j = 0; j < TN; ++j) acc[i][j] += a[i] * b[j];
        }
        __syncthreads();
    }

    const int MN = M * N;
    if (gridDim.z == 1) {
#pragma unroll
        for (int i = 0; i < TM; ++i) {
            int r = row0 + ty * TM + i;
            float4 v;
            v.x = acc[i][0]; v.y = acc[i][1]; v.z = acc[i][2]; v.w = acc[i][3];
            int c = col0 + tx * TN;
            if (bias) { v.x += bias[c]; v.y += bias[c+1]; v.z += bias[c+2]; v.w += bias[c+3]; }
            if (relu) { v.x = fmaxf(v.x,0.f); v.y = fmaxf(v.y,0.f);
                        v.z = fmaxf(v.z,0.f); v.w = fmaxf(v.w,0.f); }
            *reinterpret_cast<float4*>(&C[r * N + c]) = v;
        }
    } else {
        float* dstp = Cp + z * MN;
#pragma unroll
        for (int i = 0; i < TM; ++i) {
            int r = row0 + ty * TM + i;
            float4 v;
            v.x = acc[i][0]; v.y = acc[i][1]; v.z = acc[i][2]; v.w = acc[i][3];
            *reinterpret_cast<float4*>(&dstp[r * N + col0 + tx * TN]) = v;
        }
    }
}

// ---------- split-K reduce: C = relu?(sum_z Cp[z] + bias) ----------
__global__ void k_reduceK(const float* __restrict__ Cp, const float* __restrict__ bias,
                          float* __restrict__ C, int MN, int N, int nz, int relu) {
    int i4 = (blockIdx.x * 256 + threadIdx.x) * 4;
    if (i4 >= MN) return;
    float4 acc = *reinterpret_cast<const float4*>(&Cp[i4]);
    for (int z = 1; z < nz; ++z) {
        float4 t = *reinterpret_cast<const float4*>(&Cp[z * MN + i4]);
        acc.x += t.x; acc.y += t.y; acc.z += t.z; acc.w += t.w;
    }
    if (bias) {
        int c = i4 % N;
        acc.x += bias[c]; acc.y += bias[c + 1]; acc.z += bias[c + 2]; acc.w += bias[c + 3];
    }
    if (relu) {
        acc.x = fmaxf(acc.x, 0.f); acc.y = fmaxf(acc.y, 0.f);
        acc.z = fmaxf(acc.z, 0.f); acc.w = fmaxf(acc.w, 0.f);
    }
    *reinterpret_cast<float4*>(&C[i4]) = acc;
}

// ---------- NNConv message + scatter, grouped by combo ----------
// grid = NCOMBO*2 blocks; block = 256 (8 edge-slots x 32 output cols).
// W column lives in 64 VGPRs (loaded once); x rows staged via LDS broadcast.
// No __syncthreads in the hot loop: each 32-lane group only touches its own
// LDS slot (same-wave LDS RAW is ordered). 1-deep prefetch of next edge.
__global__ __launch_bounds__(256) void k_msg_g(
    const float* __restrict__ x, const float* __restrict__ wtab,
    const int* __restrict__ offs, const int2* __restrict__ esd,
    float* __restrict__ out) {
    const int c    = blockIdx.x >> 1;          // combo id
    const int sub  = blockIdx.x & 1;           // split half
    const int t    = threadIdx.x;
    const int o    = t & 31;                   // output column
    const int slot = t >> 5;                   // 0..7 edge slot
    const int e0 = offs[c], e1 = offs[c + 1];
    if (e0 + sub * 8 >= e1) return;            // nothing for this half

    // W column -> registers (64 VGPR), read once per block
    const float* w = wtab + c * 2048 + o;
    float wr[64];
#pragma unroll
    for (int k = 0; k < 64; ++k) wr[k] = w[k * 32];

    __shared__ float sx[8][64];

    int idx  = e0 + sub * 8 + slot;            // this slot's first edge
    bool act = idx < e1;
    float xa = 0.f, xb = 0.f; int dcur = 0;
    if (act) {
        int2 sd = esd[idx];
        dcur = sd.y;
        const float* xr = x + sd.x * 64;
        xa = xr[o]; xb = xr[o + 32];
    }
    while (__any(act)) {
        if (act) { sx[slot][o] = xa; sx[slot][o + 32] = xb; }
        // prefetch next edge's x row while we compute
        int nidx  = idx + 16;
        bool nact = nidx < e1;
        float na = 0.f, nb = 0.f; int nd = 0;
        if (nact) {
            int2 sd = esd[nidx];
            nd = sd.y;
            const float* xr = x + sd.x * 64;
            na = xr[o]; nb = xr[o + 32];
        }
        if (act) {
            float acc = 0.f;
            const float4* xv = reinterpret_cast<const float4*>(sx[slot]);
#pragma unroll
            for (int k4 = 0; k4 < 16; ++k4) {
                float4 v = xv[k4];
                acc += v.x * wr[4 * k4 + 0];
                acc += v.y * wr[4 * k4 + 1];
                acc += v.z * wr[4 * k4 + 2];
                acc += v.w * wr[4 * k4 + 3];
            }
            atomicAdd(&out[dcur * 32 + o], acc);
        }
        idx = nidx; act = nact; xa = na; xb = nb; dcur = nd;
    }
}

// ---------- fused readout tail: f2[1024,128] -> f3 -> f4 -> out[1024] ----------
__global__ __launch_bounds__(256) void k_tail(
    const float* __restrict__ f2,
    const float* __restrict__ mW3, const float* __restrict__ mb3,
    const float* __restrict__ mW4, const float* __restrict__ mb4,
    const float* __restrict__ mW5, const float* __restrict__ mb5,
    float* __restrict__ outv) {
    __shared__ float s2[4][128];
    __shared__ float s3[4][32];
    __shared__ float s4[4][8];
    const int w = threadIdx.x >> 6, lane = threadIdx.x & 63;
    const int g = blockIdx.x * 4 + w;
    s2[w][lane] = f2[g * 128 + lane];
    s2[w][64 + lane] = f2[g * 128 + 64 + lane];
    __syncthreads();
    if (lane < 32) {
        float acc = mb3[lane];
#pragma unroll 8
        for (int k = 0; k < 128; ++k) acc += s2[w][k] * mW3[k * 32 + lane];
        s3[w][lane] = fmaxf(acc, 0.f);
    }
    __syncthreads();
    if (lane < 8) {
        float acc = mb4[lane];
#pragma unroll
        for (int k = 0; k < 32; ++k) acc += s3[w][k] * mW4[k * 8 + lane];
        s4[w][lane] = fmaxf(acc, 0.f);
    }
    __syncthreads();
    if (lane == 0) {
        float acc = mb5[0];
#pragma unroll
        for (int k = 0; k < 8; ++k) acc += s4[w][k] * mW5[k];
        outv[g] = acc;
    }
}

extern "C" void kernel_launch(void* const* d_in, const int* in_sizes, int n_in,
                              void* d_out, int out_size, void* d_ws, size_t ws_size,
                              hipStream_t stream) {
    const int*   nf      = (const int*)d_in[0];
    const int*   ef      = (const int*)d_in[1];
    const int*   eidx    = (const int*)d_in[2];
    const float* atom_emb= (const float*)d_in[4];
    const float* bond_emb= (const float*)d_in[5];
    const float* gW1     = (const float*)d_in[6];
    const float* gW2     = (const float*)d_in[7];
    const float* gW3     = (const float*)d_in[8];
    const float* root    = (const float*)d_in[9];
    const float* cbias   = (const float*)d_in[10];
    const float* mW1     = (const float*)d_in[11];
    const float* mb1     = (const float*)d_in[12];
    const float* mW2     = (const float*)d_in[13];
    const float* mb2     = (const float*)d_in[14];
    const float* mW3     = (const float*)d_in[15];
    const float* mb3     = (const float*)d_in[16];
    const float* mW4     = (const float*)d_in[17];
    const float* mb4     = (const float*)d_in[18];
    const float* mW5     = (const float*)d_in[19];
    const float* mb5     = (const float*)d_in[20];

    const int* src = eidx;
    const int* dst = eidx + NEDGES;

    float* ws = (float*)d_ws;
    float* x    = ws;                       // 40960*64   = 2621440
    float* out  = x + 2621440;              // 40960*32   = 1310720
    float* etab = out + 1310720;            // 512*16     = 8192
    float* h1   = etab + 8192;              // 512*1024   = 524288
    float* h2   = h1 + 524288;              // 512*256    = 131072
    float* wtab = h2 + 131072;              // 512*2048   = 1048576
    float* f1   = wtab + 1048576;           // 1024*256   = 262144
    float* f2   = f1 + 262144;              // 1024*128   = 131072
    float* part = f2 + 131072;              // 2097152 (8 MB split-K partials, reused)
    int*   cid  = (int*)(part + 2097152);   // 81920 ints
    int2*  esd  = (int2*)(cid + 81920);     // 81920 int2 (sorted (src,dst))
    int*   hist = (int*)(esd + 81920);      // 512
    int*   offs = hist + 512;               // 513
    int*   curs = offs + 513;               // 512

    // 1. atom encoder + root transform (agg initializer)
    k_atom<<<NNODES * 64 / 256, 256, 0, stream>>>(nf, atom_emb, x);
    k_rootinit<<<NNODES * 32 / 256, 256, 0, stream>>>(x, root, cbias, out);
    // 2. counting-sort edges by combo id
    k_zero512<<<1, 512, 0, stream>>>(hist);
    k_cid_hist<<<NEDGES / 256, 256, 0, stream>>>(ef, cid, hist);
    k_scan<<<1, 512, 0, stream>>>(hist, offs, curs);
    k_scatter<<<NEDGES / 256, 256, 0, stream>>>(cid, src, dst, curs, esd);
    // 3. dedup'd edge embeddings + edge MLP on 512 unique combos
    k_etab<<<NCOMBO * 16 / 256, 256, 0, stream>>>(bond_emb, etab);
    k_gemm_naive<<<NCOMBO * 1024 / 256, 256, 0, stream>>>(etab, gW1, nullptr, h1,
                                                          NCOMBO, 1024, 16, 1);
    // h2 = relu(h1 @ gW2): 512x256, K=1024, split 16x64
    k_gemm_tiled<64, 64, 16, 4, 4><<<dim3(4, 8, 16), 256, 0, stream>>>(
        h1, gW2, nullptr, nullptr, part, NCOMBO, 256, 1024, 64, 0);
    k_reduceK<<<131072 / 1024, 256, 0, stream>>>(part, nullptr, h2, 131072, 256, 16, 1);
    // wtab = h2 @ gW3: 512x2048, K=256, split 2x128
    k_gemm_tiled<64, 64, 16, 4, 4><<<dim3(32, 8, 2), 256, 0, stream>>>(
        h2, gW3, nullptr, nullptr, part, NCOMBO, 2048, 256, 128, 0);
    k_reduceK<<<1048576 / 1024, 256, 0, stream>>>(part, nullptr, wtab, 1048576, 2048, 2, 0);
    // 4. per-edge message + scatter-add, grouped by combo
    k_msg_g<<<NCOMBO * 2, 256, 0, stream>>>(x, wtab, offs, esd, out);
    // 5. readout: f1 = relu(dense @ mW1 + mb1), dense == out viewed [1024,1280]
    k_gemm_tiled<64, 64, 16, 4, 4><<<dim3(4, 16, 8), 256, 0, stream>>>(
        out, mW1, nullptr, nullptr, part, NG, 256, 1280, 160, 0);
    k_reduceK<<<262144 / 1024, 256, 0, stream>>>(part, mb1, f1, 262144, 256, 8, 1);
    // f2 = relu(f1 @ mW2 + mb2): 1024x128, K=256, split 4x64
    k_gemm_tiled<64, 64, 16, 4, 4><<<dim3(2, 16, 4), 256, 0, stream>>>(
        f1, mW2, nullptr, nullptr, part, NG, 128, 256, 64, 0);
    k_reduceK<<<131072 / 1024, 256, 0, stream>>>(part, mb2, f2, 131072, 128, 4, 1);
    // 6. fused tail: f3, f4, final
    k_tail<<<NG / 4, 256, 0, stream>>>(f2, mW3, mb3, mW4, mb4, mW5, mb5, (float*)d_out);
}